// Round 9
// baseline (84.571 us; speedup 1.0000x reference)
//
#include <hip/hip_runtime.h>

// 20-qubit statevector, 8 layers {Ry x20, CZ chain, Rzz chain}, out = |psi|^2.
// R9 = R8 + non-temporal psi/out stores (stream dirty data to L3 during the
// kernel instead of a bulk L2 writeback bubble at each kernel boundary) and
// D-table loads issued before psi loads (table->LDS fill waits vmcnt(2),
// psi loads stay in flight under it).
// Structure: 512 blocks x 512 threads, 2 blocks/CU, 2048-amp tiles; hoisted
// D-tables (init precomputes layers 1..6); butterfly passes with DPP lane
// rotations + two XOR-swizzled LDS transposes.
// Schedule (1 pass/layer):
//  LOW resident flat 0..10:  A=Ry_l(0..10), D_l, B=Ry_{l+1}(0..10)
//  HI  resident {0,1}u{11..19}: A=Ry_l(11..19), D_l, B=Ry_{l+1}(11..19)
// Tile n[10:0], thread t[8:0], amp j[1:0]:
//  L0: reg={n1,n0} lanes={n7..n2} wave={n10..n8}  (global-coalesced)
//  Q : reg={n7,n6} lanes={n8,n9,n10,n3,n4,n5} wave={n2,n1,n0}
// HI global map: x = j[1:0] | cid<<2 | (m>>2)<<11 ; cid=((blk>>7)&3)|((blk&127)<<2)
// so the 4 blocks sharing each 128B line sit on one XCD (blk%8 equal).
// DPP semantics: row_shr:N = from lane i-N, row_shl:N = from lane i+N.

#define QN 20

typedef float vf4 __attribute__((ext_vector_type(4)));

__device__ __forceinline__ float2 cmulf(float2 a, float2 b) {
    return make_float2(a.x * b.x - a.y * b.y, a.x * b.y + a.y * b.x);
}

// ---- rotation on register bits: w = (cos, sin) -----------------------------
__device__ __forceinline__ void rot2c(float2& x0, float2& x1, float2 w) {
    float2 t0 = make_float2(w.x * x0.x - w.y * x1.x, w.x * x0.y - w.y * x1.y);
    float2 t1 = make_float2(w.y * x0.x + w.x * x1.x, w.y * x0.y + w.x * x1.y);
    x0 = t0; x1 = t1;
}
__device__ __forceinline__ void rot4c(float2& a0, float2& a1, float2& a2, float2& a3,
                                      float2 wa, float2 wb) {
    rot2c(a0, a1, wa); rot2c(a2, a3, wa);
    rot2c(a0, a2, wb); rot2c(a1, a3, wb);
}

// ---- DPP cross-lane partner fetch (xor distance X in {1,2,4,8}) ------------
template<int X>
__device__ __forceinline__ float2 xpart(float2 v, int t) {
    int sx = __float_as_int(v.x), sy = __float_as_int(v.y);
    if constexpr (X == 4) {
        // row_shr:4 (0x114): lane i <- i-4 (t&4=1 side); row_shl:4 (0x104):
        // lane i <- i+4 (t&4=0 side); select by side.
        int ax = __builtin_amdgcn_update_dpp(sx, sx, 0x114, 0xF, 0xF, false);
        int ay = __builtin_amdgcn_update_dpp(sy, sy, 0x114, 0xF, 0xF, false);
        int bx = __builtin_amdgcn_update_dpp(sx, sx, 0x104, 0xF, 0xF, false);
        int by = __builtin_amdgcn_update_dpp(sy, sy, 0x104, 0xF, 0xF, false);
        bool hi = (t & 4) != 0;
        return make_float2(__int_as_float(hi ? ax : bx), __int_as_float(hi ? ay : by));
    } else {
        // xor1: quad_perm[1,0,3,2]=0xB1; xor2: quad_perm[2,3,0,1]=0x4E;
        // xor8: row_ror:8=0x128 ((i+8)%16 == i^8 within a 16-row)
        constexpr int ctrl = (X == 1) ? 0xB1 : (X == 2) ? 0x4E : 0x128;
        return make_float2(
            __int_as_float(__builtin_amdgcn_update_dpp(sx, sx, ctrl, 0xF, 0xF, false)),
            __int_as_float(__builtin_amdgcn_update_dpp(sy, sy, ctrl, 0xF, 0xF, false)));
    }
}

// Ry on a lane bit: own' = c*own + (side? +s : -s)*partner
template<int X>
__device__ __forceinline__ void lrot4(float2& a0, float2& a1, float2& a2, float2& a3,
                                      float2 w, int t) {
    float ss = (t & X) ? w.y : -w.y;
    float2 p0 = xpart<X>(a0, t), p1 = xpart<X>(a1, t),
           p2 = xpart<X>(a2, t), p3 = xpart<X>(a3, t);
    a0 = make_float2(fmaf(ss, p0.x, w.x * a0.x), fmaf(ss, p0.y, w.x * a0.y));
    a1 = make_float2(fmaf(ss, p1.x, w.x * a1.x), fmaf(ss, p1.y, w.x * a1.y));
    a2 = make_float2(fmaf(ss, p2.x, w.x * a2.x), fmaf(ss, p2.y, w.x * a2.y));
    a3 = make_float2(fmaf(ss, p3.x, w.x * a3.x), fmaf(ss, p3.y, w.x * a3.y));
}

// ---- diagonal (CZ chain + Rzz chain) phase ---------------------------------
__device__ __forceinline__ float2 dphase(int x, const float2* Plo, const float2* Phh) {
    int y = (x ^ (x >> 1)) & 0x7FFFF;
    float2 p = cmulf(Plo[y & 1023], Phh[y >> 10]);
    int sgn = (__popc(x & (x >> 1) & 0x7FFFF) & 1) << 31;
    p.x = __int_as_float(__float_as_int(p.x) ^ sgn);
    p.y = __int_as_float(__float_as_int(p.y) ^ sgn);
    return p;
}

// 512 threads: each builds 2 Plo entries + 1 Phh entry (init only, D_0).
__device__ __forceinline__ void build_D(float2* Plo, float2* Phh,
                                        const float* __restrict__ ph, int t) {
    float pw[19];
    #pragma unroll
    for (int j = 0; j < 19; ++j) pw[j] = ph[18 - j];   // uniform loads
    float S = 0.f;
    #pragma unroll
    for (int j = 0; j < 19; ++j) S += pw[j];
    #pragma unroll
    for (int k2 = 0; k2 < 2; ++k2) {
        int i = t + (k2 << 9);
        float ang = 0.f;
        #pragma unroll
        for (int j = 0; j < 10; ++j) if ((i >> j) & 1) ang += pw[j];
        Plo[i] = make_float2(cosf(ang), sinf(ang));
    }
    {
        float a2 = -0.5f * S;
        #pragma unroll
        for (int j = 0; j < 9; ++j) if ((t >> j) & 1) a2 += pw[10 + j];
        Phh[t] = make_float2(cosf(a2), sinf(a2));
    }
}

// Pass kernels: fill Plo/Phh LDS from the precomputed global table (12 KB).
__device__ __forceinline__ void load_D(float2* Plo, float2* Phh,
                                       const float2* __restrict__ tab, int t) {
    float2 p0 = tab[t], p1 = tab[t | 512], p2 = tab[t + 1024];
    Plo[t] = p0; Plo[t | 512] = p1; Phh[t] = p2;
}

// ---- transpose 1 (L0 -> Q), 2048-amp tile ----------------------------------
// m(n): m0=n6,m1=n7,m[4:2]={n8,n9,n10},m[7:5]={n3,n4,n5},m[9:8]={n0,n1},m10=n2.
// store at p = m ^ (m[7:5]<<2).
__device__ __forceinline__ void pass_w1(float2* buf, int t,
                                        float2 a0, float2 a1, float2 a2, float2 a3) {
    int mb = ((t >> 4) & 3) | (((t >> 6) & 7) << 2) |
             (((t >> 1) & 7) << 5) | ((t & 1) << 10);
    int pb = mb ^ (((t >> 1) & 7) << 2);
    buf[pb] = a0; buf[pb | 0x100] = a1; buf[pb | 0x200] = a2; buf[pb | 0x300] = a3;
}
__device__ __forceinline__ void pass_r1(const float2* buf, int t,
                                        float2& a0, float2& a1, float2& a2, float2& a3) {
    int rb = (4 * t) ^ (((t >> 3) & 7) << 2);
    const float4* b4 = (const float4*)(buf + rb);
    float4 u = b4[0], w = b4[1];
    a0 = make_float2(u.x, u.y); a1 = make_float2(u.z, u.w);
    a2 = make_float2(w.x, w.y); a3 = make_float2(w.z, w.w);
}
// Q thread's tile-index base (j' lands at n[7:6])
__device__ __forceinline__ int q_nb(int t) {
    return ((t >> 6) & 7) | (((t >> 3) & 7) << 3) | ((t & 7) << 8);
}
// ---- transpose 2 (Q -> L0): store at q = n ^ ((n>>8)&7) --------------------
__device__ __forceinline__ void pass_w2(float2* buf, int t,
                                        float2 a0, float2 a1, float2 a2, float2 a3) {
    int q0 = q_nb(t) ^ (t & 7);
    buf[q0] = a0; buf[q0 | 0x40] = a1; buf[q0 | 0x80] = a2; buf[q0 | 0xC0] = a3;
}
__device__ __forceinline__ void pass_r2(const float2* buf, int t,
                                        float2& a0, float2& a1, float2& a2, float2& a3) {
    int rb = (4 * t) ^ (((t >> 8) & 1) << 2);
    const float4* b4 = (const float4*)(buf + rb);
    float4 u = b4[0], w = b4[1];
    float2 r0 = make_float2(u.x, u.y), r1 = make_float2(u.z, u.w),
           r2 = make_float2(w.x, w.y), r3 = make_float2(w.z, w.w);
    int k = (t >> 6) & 3;                       // wave-uniform in-quad xor
    if (k & 1) { float2 x = r0; r0 = r1; r1 = x; x = r2; r2 = r3; r3 = x; }
    if (k & 2) { float2 x = r0; r0 = r2; r2 = x; x = r1; r1 = r3; r3 = x; }
    a0 = r0; a1 = r1; a2 = r2; a3 = r3;
}

// NT store of 4 amps (two float4s) at float4-granule index base
__device__ __forceinline__ void nt_store2(float2* p,
                                          float2 a0, float2 a1, float2 a2, float2 a3) {
    vf4 s0, s1;
    s0[0] = a0.x; s0[1] = a0.y; s0[2] = a1.x; s0[3] = a1.y;
    s1[0] = a2.x; s1[1] = a2.y; s1[2] = a3.x; s1[3] = a3.y;
    vf4* vp = (vf4*)p;
    __builtin_nontemporal_store(s0, vp);
    __builtin_nontemporal_store(s1, vp + 1);
}

// ---------------- LOW kernel: tile = contiguous 2048 amps -------------------
template<bool LAST>
__global__ __launch_bounds__(512)
void low_kernel(float2* __restrict__ psi, const float2* __restrict__ cA,
                const float2* __restrict__ cB, const float2* __restrict__ tab,
                float* __restrict__ outP) {
    __shared__ __align__(16) float2 bufA[2048];
    __shared__ __align__(16) float2 bufB[2048];
    __shared__ float2 Plo[1024];
    __shared__ float2 Phh[512];
    const int t = threadIdx.x, blk = blockIdx.x;

    if (!LAST) load_D(Plo, Phh, tab, t);     // table loads issued first

    const float4* gp = (const float4*)(psi + (blk << 11));
    float4 v0 = gp[2 * t], v1 = gp[2 * t + 1];

    float2 a0 = make_float2(v0.x, v0.y), a1 = make_float2(v0.z, v0.w),
           a2 = make_float2(v1.x, v1.y), a3 = make_float2(v1.z, v1.w);

    // phase1 @L0: A flat 0..5
    rot4c(a0, a1, a2, a3, cA[0], cA[1]);
    lrot4<1>(a0, a1, a2, a3, cA[2], t);
    lrot4<2>(a0, a1, a2, a3, cA[3], t);
    lrot4<4>(a0, a1, a2, a3, cA[4], t);
    lrot4<8>(a0, a1, a2, a3, cA[5], t);

    pass_w1(bufA, t, a0, a1, a2, a3);
    __syncthreads();                     // bar1 (covers Plo/Phh fill too)
    pass_r1(bufA, t, a0, a1, a2, a3);

    // phase2 @Q: A flat 6..10
    rot4c(a0, a1, a2, a3, cA[6], cA[7]);
    lrot4<1>(a0, a1, a2, a3, cA[8], t);
    lrot4<2>(a0, a1, a2, a3, cA[9], t);
    lrot4<4>(a0, a1, a2, a3, cA[10], t);

    int nb = q_nb(t);
    if (LAST) {
        // |amp|^2 -> float transpose-2 -> coalesced float4 out (D_7 elided)
        float* bf = (float*)bufB;
        int q0 = nb ^ (t & 7);
        bf[q0]        = a0.x * a0.x + a0.y * a0.y;
        bf[q0 | 0x40] = a1.x * a1.x + a1.y * a1.y;
        bf[q0 | 0x80] = a2.x * a2.x + a2.y * a2.y;
        bf[q0 | 0xC0] = a3.x * a3.x + a3.y * a3.y;
        __syncthreads();
        int rbf = (4 * t) ^ (((t >> 8) & 1) << 2);
        float4 u = *(const float4*)(bf + rbf);
        int k = (t >> 6) & 3;
        if (k & 1) { float x = u.x; u.x = u.y; u.y = x; x = u.z; u.z = u.w; u.w = x; }
        if (k & 2) { float x = u.x; u.x = u.z; u.z = x; x = u.y; u.y = u.w; u.w = x; }
        vf4 s; s[0] = u.x; s[1] = u.y; s[2] = u.z; s[3] = u.w;
        __builtin_nontemporal_store(s, (vf4*)(outP + (blk << 11) + 4 * t));
    } else {
        int xb = blk << 11;
        a0 = cmulf(a0, dphase(xb | nb,            Plo, Phh));
        a1 = cmulf(a1, dphase(xb | nb | (1 << 6), Plo, Phh));
        a2 = cmulf(a2, dphase(xb | nb | (2 << 6), Plo, Phh));
        a3 = cmulf(a3, dphase(xb | nb | (3 << 6), Plo, Phh));
        // B flat 6..10 (still in Q)
        rot4c(a0, a1, a2, a3, cB[6], cB[7]);
        lrot4<1>(a0, a1, a2, a3, cB[8], t);
        lrot4<2>(a0, a1, a2, a3, cB[9], t);
        lrot4<4>(a0, a1, a2, a3, cB[10], t);

        pass_w2(bufB, t, a0, a1, a2, a3);
        __syncthreads();                 // bar2
        pass_r2(bufB, t, a0, a1, a2, a3);

        // phase3 @L0: B flat 0..5
        lrot4<1>(a0, a1, a2, a3, cB[2], t);
        lrot4<2>(a0, a1, a2, a3, cB[3], t);
        lrot4<4>(a0, a1, a2, a3, cB[4], t);
        lrot4<8>(a0, a1, a2, a3, cB[5], t);
        rot4c(a0, a1, a2, a3, cB[0], cB[1]);
        nt_store2(psi + (blk << 11) + 4 * t, a0, a1, a2, a3);
    }
}

// ---------------- HI kernel: tile bits m = {flat0,flat1, flat11..19} --------
__global__ __launch_bounds__(512)
void hi_kernel(float2* __restrict__ psi, const float2* __restrict__ cA,
               const float2* __restrict__ cB, const float2* __restrict__ tab) {
    __shared__ __align__(16) float2 bufA[2048];
    __shared__ __align__(16) float2 bufB[2048];
    __shared__ float2 Plo[1024];
    __shared__ float2 Phh[512];
    const int t = threadIdx.x, blk = blockIdx.x;
    const int cid = ((blk >> 7) & 3) | ((blk & 0x7F) << 2);  // line-mates co-XCD
    const int ga = (cid << 2) | ((t & 63) << 11) | (((t >> 6) & 7) << 17);

    load_D(Plo, Phh, tab, t);            // table loads issued first

    const float4* gp = (const float4*)(psi + ga);
    float4 v0 = gp[0], v1 = gp[1];

    float2 a0 = make_float2(v0.x, v0.y), a1 = make_float2(v0.z, v0.w),
           a2 = make_float2(v1.x, v1.y), a3 = make_float2(v1.z, v1.w);

    // phase1 @H0: A flat 11..14 (m2..m5 at lanes x1,x2,x4,x8)
    lrot4<1>(a0, a1, a2, a3, cA[11], t);
    lrot4<2>(a0, a1, a2, a3, cA[12], t);
    lrot4<4>(a0, a1, a2, a3, cA[13], t);
    lrot4<8>(a0, a1, a2, a3, cA[14], t);

    pass_w1(bufA, t, a0, a1, a2, a3);
    __syncthreads();                     // bar1
    pass_r1(bufA, t, a0, a1, a2, a3);

    // phase2 @Q: A flat 15..19 (m6,m7 reg; m8,m9,m10 lanes x1,x2,x4)
    rot4c(a0, a1, a2, a3, cA[15], cA[16]);
    lrot4<1>(a0, a1, a2, a3, cA[17], t);
    lrot4<2>(a0, a1, a2, a3, cA[18], t);
    lrot4<4>(a0, a1, a2, a3, cA[19], t);

    int mb = q_nb(t);
    int xbase = (mb & 3) | (cid << 2) | ((mb >> 2) << 11);
    a0 = cmulf(a0, dphase(xbase,             Plo, Phh));
    a1 = cmulf(a1, dphase(xbase | (1 << 15), Plo, Phh));
    a2 = cmulf(a2, dphase(xbase | (2 << 15), Plo, Phh));
    a3 = cmulf(a3, dphase(xbase | (3 << 15), Plo, Phh));

    // B flat 15..19 (still in Q)
    rot4c(a0, a1, a2, a3, cB[15], cB[16]);
    lrot4<1>(a0, a1, a2, a3, cB[17], t);
    lrot4<2>(a0, a1, a2, a3, cB[18], t);
    lrot4<4>(a0, a1, a2, a3, cB[19], t);

    pass_w2(bufB, t, a0, a1, a2, a3);
    __syncthreads();                     // bar2
    pass_r2(bufB, t, a0, a1, a2, a3);

    // phase3 @H0: B flat 11..14
    lrot4<1>(a0, a1, a2, a3, cB[11], t);
    lrot4<2>(a0, a1, a2, a3, cB[12], t);
    lrot4<4>(a0, a1, a2, a3, cB[13], t);
    lrot4<8>(a0, a1, a2, a3, cB[14], t);

    nt_store2(psi + ga, a0, a1, a2, a3);
}

// ---------------- INIT kernel: synth Ry_0|0>, D_0, B = Ry_1(11..19) ---------
// Also dumps cos/sin(theta/2) coeffs AND the D-tables for layers 1..6.
__global__ __launch_bounds__(512)
void init_kernel(float2* __restrict__ psi, const float* __restrict__ th,
                 const float* __restrict__ ph, float2* __restrict__ cw,
                 float2* __restrict__ Dtab) {
    __shared__ __align__(16) float2 bufA[2048];   // holds Alo/Ahi/cAi/cBi
    __shared__ __align__(16) float2 bufB[2048];
    __shared__ float2 Plo[1024];
    __shared__ float2 Phh[512];
    float* Alo = (float*)bufA;           // floats [0..1023]
    float* Ahi = Alo + 1024;             // floats [1024..2047]
    float2* cAi = bufA + 1024;           // float2 [1024..1043]
    float2* cBi = bufA + 1056;           // float2 [1056..1075]
    const int t = threadIdx.x, blk = blockIdx.x;
    const int cid = ((blk >> 7) & 3) | ((blk & 0x7F) << 2);
    const int ga = (cid << 2) | ((t & 63) << 11) | (((t >> 6) & 7) << 17);

    // ---- D-table generation for layers 1..6 (one entry per thread) ----
    {
        int g = blk * 512 + t;
        if (g < 6 * 1536) {
            int l = (g / 1536) + 1;
            int idx = g - (l - 1) * 1536;
            const float* pp = ph + 19 * l;
            float pw[19];
            #pragma unroll
            for (int j = 0; j < 19; ++j) pw[j] = pp[18 - j];
            float2 e;
            if (idx < 1024) {
                float ang = 0.f;
                #pragma unroll
                for (int j = 0; j < 10; ++j) if ((idx >> j) & 1) ang += pw[j];
                e = make_float2(cosf(ang), sinf(ang));
            } else {
                float S = 0.f;
                #pragma unroll
                for (int j = 0; j < 19; ++j) S += pw[j];
                int i2 = idx - 1024;
                float a2 = -0.5f * S;
                #pragma unroll
                for (int j = 0; j < 9; ++j) if ((i2 >> j) & 1) a2 += pw[10 + j];
                e = make_float2(cosf(a2), sinf(a2));
            }
            Dtab[g] = e;
        }
    }

    if (t < 256) {
        int l = t >> 5, f = t & 31;
        if (f < 20) {
            double a = 0.5 * (double)th[l * 20 + 19 - f];
            float2 w = make_float2((float)cos(a), (float)sin(a));
            cw[l * 20 + f] = w;
            if (l == 0) cAi[f] = w;
            else if (l == 1) cBi[f] = w;
        }
    }
    __syncthreads();                     // bar0: cAi/cBi ready

    build_D(Plo, Phh, ph, t);            // D_0 local (used only here)
    #pragma unroll
    for (int k2 = 0; k2 < 2; ++k2) {
        int i = t + (k2 << 9);
        float pl = 1.f, ph2 = 1.f;
        #pragma unroll
        for (int j = 0; j < 10; ++j) {
            pl  *= ((i >> j) & 1) ? cAi[j].y      : cAi[j].x;
            ph2 *= ((i >> j) & 1) ? cAi[10 + j].y : cAi[10 + j].x;
        }
        Alo[i] = pl; Ahi[i] = ph2;
    }
    __syncthreads();                     // bar1: tables ready

    // synth product state directly in Q layout, D_0 fused
    int mb = q_nb(t);
    int xbase = (mb & 3) | (cid << 2) | ((mb >> 2) << 11);
    float2 a0, a1, a2, a3;
    {
        int x0 = xbase,             x1 = xbase | (1 << 15),
            x2 = xbase | (2 << 15), x3 = xbase | (3 << 15);
        float m0 = Alo[x0 & 1023] * Ahi[x0 >> 10];
        float m1 = Alo[x1 & 1023] * Ahi[x1 >> 10];
        float m2 = Alo[x2 & 1023] * Ahi[x2 >> 10];
        float m3 = Alo[x3 & 1023] * Ahi[x3 >> 10];
        float2 d0 = dphase(x0, Plo, Phh), d1 = dphase(x1, Plo, Phh),
               d2 = dphase(x2, Plo, Phh), d3 = dphase(x3, Plo, Phh);
        a0 = make_float2(m0 * d0.x, m0 * d0.y);
        a1 = make_float2(m1 * d1.x, m1 * d1.y);
        a2 = make_float2(m2 * d2.x, m2 * d2.y);
        a3 = make_float2(m3 * d3.x, m3 * d3.y);
    }

    // B = Ry_1 flat 15..19 in Q
    rot4c(a0, a1, a2, a3, cBi[15], cBi[16]);
    lrot4<1>(a0, a1, a2, a3, cBi[17], t);
    lrot4<2>(a0, a1, a2, a3, cBi[18], t);
    lrot4<4>(a0, a1, a2, a3, cBi[19], t);

    pass_w2(bufB, t, a0, a1, a2, a3);
    __syncthreads();                     // bar2 (cBi reads below pre-bar0 data)
    pass_r2(bufB, t, a0, a1, a2, a3);

    // phase3 @H0: B flat 11..14
    lrot4<1>(a0, a1, a2, a3, cBi[11], t);
    lrot4<2>(a0, a1, a2, a3, cBi[12], t);
    lrot4<4>(a0, a1, a2, a3, cBi[13], t);
    lrot4<8>(a0, a1, a2, a3, cBi[14], t);

    nt_store2(psi + ga, a0, a1, a2, a3);
}

extern "C" void kernel_launch(void* const* d_in, const int* in_sizes, int n_in,
                              void* d_out, int out_size, void* d_ws, size_t ws_size,
                              hipStream_t stream) {
    (void)in_sizes; (void)n_in; (void)out_size; (void)ws_size;
    const float* th = (const float*)d_in[0];   // (8,20)
    const float* ph = (const float*)d_in[1];   // (8,19)
    float2* psi = (float2*)d_ws;               // 2^20 complex64 = 8 MB
    float2* cw  = (float2*)((char*)d_ws + (8u << 20));              // coeffs
    float2* Dt  = (float2*)((char*)d_ws + (8u << 20) + 4096);       // 6x1536
    float* out = (float*)d_out;

    init_kernel      <<<512, 512, 0, stream>>>(psi, th, ph, cw, Dt);
    low_kernel<false><<<512, 512, 0, stream>>>(psi, cw + 1 * 20, cw + 2 * 20, Dt + 0 * 1536, nullptr);
    hi_kernel        <<<512, 512, 0, stream>>>(psi, cw + 2 * 20, cw + 3 * 20, Dt + 1 * 1536);
    low_kernel<false><<<512, 512, 0, stream>>>(psi, cw + 3 * 20, cw + 4 * 20, Dt + 2 * 1536, nullptr);
    hi_kernel        <<<512, 512, 0, stream>>>(psi, cw + 4 * 20, cw + 5 * 20, Dt + 3 * 1536);
    low_kernel<false><<<512, 512, 0, stream>>>(psi, cw + 5 * 20, cw + 6 * 20, Dt + 4 * 1536, nullptr);
    hi_kernel        <<<512, 512, 0, stream>>>(psi, cw + 6 * 20, cw + 7 * 20, Dt + 5 * 1536);
    low_kernel<true ><<<512, 512, 0, stream>>>(psi, cw + 7 * 20, cw + 7 * 20, nullptr, out);
}